// Round 1
// baseline (949.009 us; speedup 1.0000x reference)
//
#include <hip/hip_runtime.h>

typedef unsigned short u16;
typedef unsigned int   u32;

#define B_   8
#define C_   128
#define H_   128
#define W_   128
#define NH   4
#define D_   32
#define HW_  16384
#define SCALE 0.17677669529663687f

__device__ __forceinline__ float bf2f_u(u16 u) { union { u32 i; float f; } x; x.i = ((u32)u) << 16; return x.f; }
__device__ __forceinline__ float bflo(u32 u)   { union { u32 i; float f; } x; x.i = u << 16; return x.f; }
__device__ __forceinline__ float bfhi(u32 u)   { union { u32 i; float f; } x; x.i = u & 0xffff0000u; return x.f; }
__device__ __forceinline__ u16   f2bf(float f) {
  union { float f; u32 i; } x; x.f = f;
  u32 i = x.i;
  return (u16)((i + 0x7fffu + ((i >> 16) & 1u)) >> 16);
}

// ---------------------------------------------------------------------------
// K1: qkv 1x1 conv (GEMM). x:[B,C,HW] f32, wqkv:[384,128] f32
// -> q/k/v bf16, each laid out [B, head, pixel, dim] (dim=32 contiguous)
// ---------------------------------------------------------------------------
__global__ __launch_bounds__(256) void k_qkv(const float* __restrict__ x,
                                             const float* __restrict__ wqkv,
                                             u16* __restrict__ qkvb) {
  __shared__ u16 xs[128 * 128];   // [c][p] bf16, 32 KB
  __shared__ u16 wsT[128 * 72];   // [c][o_local] padded, 18 KB
  const int tid = threadIdx.x;
  const int p0 = blockIdx.x * 128;
  const int o0 = blockIdx.y * 64;
  const int b  = blockIdx.z;
  const float* xb = x + (size_t)b * (C_ * HW_);

  for (int i = tid; i < 64 * 128; i += 256) {
    int o = i >> 7, cc = i & 127;
    wsT[cc * 72 + o] = f2bf(wqkv[(o0 + o) * 128 + cc]);
  }
  for (int i = tid; i < 128 * 32; i += 256) {
    int cr = i >> 5, pc = (i & 31) * 4;
    float4 v4 = *(const float4*)(xb + (size_t)cr * HW_ + p0 + pc);
    u16* d = &xs[cr * 128 + pc];
    d[0] = f2bf(v4.x); d[1] = f2bf(v4.y); d[2] = f2bf(v4.z); d[3] = f2bf(v4.w);
  }
  __syncthreads();

  const int oy = tid >> 5, px = tid & 31;
  float acc[8][4];
  #pragma unroll
  for (int i = 0; i < 8; ++i)
    #pragma unroll
    for (int j = 0; j < 4; ++j) acc[i][j] = 0.f;

  for (int c = 0; c < 128; ++c) {
    u32 a4[4];
    *(uint4*)a4 = *(const uint4*)&wsT[c * 72 + oy * 8];
    float a[8];
    #pragma unroll
    for (int t = 0; t < 4; ++t) { a[2 * t] = bflo(a4[t]); a[2 * t + 1] = bfhi(a4[t]); }
    float bx[4];
    #pragma unroll
    for (int j = 0; j < 4; ++j) bx[j] = bf2f_u(xs[c * 128 + px + j * 32]);
    #pragma unroll
    for (int i = 0; i < 8; ++i)
      #pragma unroll
      for (int j = 0; j < 4; ++j) acc[i][j] += a[i] * bx[j];
  }
  __syncthreads();

  // transpose through LDS so global stores are contiguous
  u16* ldsT = xs;  // [p][72], 128*72 u16 fits in xs
  #pragma unroll
  for (int i = 0; i < 8; ++i)
    #pragma unroll
    for (int j = 0; j < 4; ++j)
      ldsT[(px + j * 32) * 72 + oy * 8 + i] = f2bf(acc[i][j]);
  __syncthreads();

  const int sel   = o0 >> 7;            // 0=q 1=k 2=v
  const int headb = (o0 & 127) >> 5;    // 0 or 2
  u16* ob = qkvb + (size_t)sel * ((size_t)B_ * NH * HW_ * D_);
  for (int ci = tid; ci < 1024; ci += 256) {
    int ho = ci >> 9, cc = ci & 511;
    int p = cc >> 2, quad = cc & 3;
    uint4 val = *(const uint4*)&ldsT[p * 72 + ho * 32 + quad * 8];
    size_t doff = ((size_t)((b * NH + headb + ho) * HW_ + p0 + p)) * D_ + quad * 8;
    *(uint4*)(ob + doff) = val;
  }
}

// ---------------------------------------------------------------------------
// K2/K3: axis attention. block = (line, head, b).
// axis=0: H-attention (line = row i, positions along W)
// axis=1: W-attention (line = col w, positions along H)
// output plane layout: [b][c][line][pos] (H: = NCHW; W: transposed planes)
// ---------------------------------------------------------------------------
__global__ __launch_bounds__(256) void k_attn(const u16* __restrict__ qb,
                                              const u16* __restrict__ kb,
                                              const u16* __restrict__ vb,
                                              const float* __restrict__ gp,
                                              u16* __restrict__ outb,
                                              const int axis) {
  __shared__ float ks[128 * 32];
  __shared__ float vs[128 * 32];
  __shared__ float dec[128];
  const int tid = threadIdx.x;
  const int line = blockIdx.x, head = blockIdx.y, b = blockIdx.z;
  const size_t base = (size_t)(b * NH + head) * HW_ * D_;

  if (tid < 128) dec[tid] = __expf(-gp[0] * (float)tid);

  for (int ci = tid; ci < 1024; ci += 256) {
    int z = ci >> 3, part = (ci & 7) * 4;
    size_t off = base + (size_t)(axis ? (z * 128 + line) : (line * 128 + z)) * D_ + part;
    u32 k2[2], v2[2];
    *(uint2*)k2 = *(const uint2*)(kb + off);
    *(uint2*)v2 = *(const uint2*)(vb + off);
    float* kd = &ks[z * 32 + part];
    float* vd = &vs[z * 32 + part];
    kd[0] = bflo(k2[0]); kd[1] = bfhi(k2[0]); kd[2] = bflo(k2[1]); kd[3] = bfhi(k2[1]);
    vd[0] = bflo(v2[0]); vd[1] = bfhi(v2[0]); vd[2] = bflo(v2[1]); vd[3] = bfhi(v2[1]);
  }

  const int j = tid >> 1, hh = tid & 1;
  float qr[32];
  {
    size_t qoff = base + (size_t)(axis ? (j * 128 + line) : (line * 128 + j)) * D_;
    u32 tmp[16];
    const uint4* qp = (const uint4*)(qb + qoff);
    *(uint4*)&tmp[0]  = qp[0];
    *(uint4*)&tmp[4]  = qp[1];
    *(uint4*)&tmp[8]  = qp[2];
    *(uint4*)&tmp[12] = qp[3];
    #pragma unroll
    for (int t = 0; t < 16; ++t) { qr[2 * t] = bflo(tmp[t]); qr[2 * t + 1] = bfhi(tmp[t]); }
  }
  __syncthreads();

  const int z0 = hh * 64;
  float s[64];
  #pragma unroll
  for (int zz = 0; zz < 64; ++zz) {
    const float* kp = &ks[(z0 + zz) * 32];
    float d0 = 0, d1 = 0, d2 = 0, d3 = 0;
    #pragma unroll
    for (int c = 0; c < 32; c += 4) {
      float4 kv = *(const float4*)(kp + c);
      d0 += qr[c] * kv.x; d1 += qr[c + 1] * kv.y;
      d2 += qr[c + 2] * kv.z; d3 += qr[c + 3] * kv.w;
    }
    s[zz] = ((d0 + d1) + (d2 + d3)) * SCALE;
  }

  float m = -1e30f;
  #pragma unroll
  for (int zz = 0; zz < 64; ++zz) m = fmaxf(m, s[zz]);
  m = fmaxf(m, __shfl_xor(m, 1));
  float l = 0.f;
  #pragma unroll
  for (int zz = 0; zz < 64; ++zz) { float e = __expf(s[zz] - m); s[zz] = e; l += e; }
  l += __shfl_xor(l, 1);
  const float inv = 1.f / l;

  float acc[32];
  #pragma unroll
  for (int c = 0; c < 32; ++c) acc[c] = 0.f;
  #pragma unroll
  for (int zz = 0; zz < 64; ++zz) {
    int z = z0 + zz;
    int ad = j - z; if (ad < 0) ad = -ad;
    float w = s[zz] * inv * dec[ad];
    const float* vp = &vs[z * 32];
    #pragma unroll
    for (int c = 0; c < 32; c += 4) {
      float4 vv = *(const float4*)(vp + c);
      acc[c] += w * vv.x; acc[c + 1] += w * vv.y;
      acc[c + 2] += w * vv.z; acc[c + 3] += w * vv.w;
    }
  }
  #pragma unroll
  for (int c = 0; c < 32; ++c) acc[c] += __shfl_xor(acc[c], 1);

  if (hh == 0) {
    #pragma unroll
    for (int c = 0; c < 32; ++c) {
      size_t o = ((size_t)((b * C_ + head * D_ + c) * 128 + line)) * 128 + j;
      outb[o] = f2bf(acc[c]);
    }
  }
}

// ---------------------------------------------------------------------------
// K4: combine out_h + out_w^T, then depthwise 3x3 SAME conv, per (b,c) plane
// ---------------------------------------------------------------------------
__global__ __launch_bounds__(256) void k_conv(const u16* __restrict__ hb,
                                              const u16* __restrict__ wb,
                                              const float* __restrict__ wdw,
                                              float* __restrict__ convo) {
  __shared__ u16 t[128 * 136];  // padded rows (272 B, 16B aligned)
  const int tid = threadIdx.x;
  const int c = blockIdx.x, b = blockIdx.y;
  const size_t pb = (size_t)(b * C_ + c) * HW_;

  // copy H-attention plane (already [i][j])
  for (int i = tid; i < 2048; i += 256) {
    int e = i * 8; int r = e >> 7, col = e & 127;
    *(uint4*)&t[r * 136 + col] = *(const uint4*)(hb + pb + e);
  }
  __syncthreads();
  // add W-attention plane transposed ([w][h] -> [h][w])
  for (int i = tid; i < 4096; i += 256) {
    int e = i * 4; int wr = e >> 7, hc = e & 127;
    u32 u2[2]; *(uint2*)u2 = *(const uint2*)(wb + pb + e);
    float f0 = bflo(u2[0]), f1 = bfhi(u2[0]), f2v = bflo(u2[1]), f3 = bfhi(u2[1]);
    t[(hc + 0) * 136 + wr] = f2bf(bf2f_u(t[(hc + 0) * 136 + wr]) + f0);
    t[(hc + 1) * 136 + wr] = f2bf(bf2f_u(t[(hc + 1) * 136 + wr]) + f1);
    t[(hc + 2) * 136 + wr] = f2bf(bf2f_u(t[(hc + 2) * 136 + wr]) + f2v);
    t[(hc + 3) * 136 + wr] = f2bf(bf2f_u(t[(hc + 3) * 136 + wr]) + f3);
  }
  __syncthreads();

  float k9[9];
  #pragma unroll
  for (int i = 0; i < 9; ++i) k9[i] = wdw[c * 9 + i];

  for (int px = tid; px < HW_; px += 256) {
    int r = px >> 7, col = px & 127;
    float a = 0.f;
    #pragma unroll
    for (int di = 0; di < 3; ++di) {
      int rr = r + di - 1;
      if (rr < 0 || rr > 127) continue;
      #pragma unroll
      for (int dj = 0; dj < 3; ++dj) {
        int cc2 = col + dj - 1;
        if (cc2 < 0 || cc2 > 127) continue;
        a += k9[di * 3 + dj] * bf2f_u(t[rr * 136 + cc2]);
      }
    }
    convo[pb + px] = a;
  }
}

// ---------------------------------------------------------------------------
// K5: proj 1x1 conv (GEMM) -> d_out f32 NCHW
// ---------------------------------------------------------------------------
__global__ __launch_bounds__(256) void k_proj(const float* __restrict__ cin,
                                              const float* __restrict__ wp,
                                              float* __restrict__ out) {
  __shared__ u16 xs[128 * 128];
  __shared__ u16 wsT[128 * 72];
  const int tid = threadIdx.x;
  const int p0 = blockIdx.x * 128;
  const int o0 = blockIdx.y * 64;
  const int b  = blockIdx.z;
  const float* xb = cin + (size_t)b * (C_ * HW_);

  for (int i = tid; i < 64 * 128; i += 256) {
    int o = i >> 7, cc = i & 127;
    wsT[cc * 72 + o] = f2bf(wp[(o0 + o) * 128 + cc]);
  }
  for (int i = tid; i < 128 * 32; i += 256) {
    int cr = i >> 5, pc = (i & 31) * 4;
    float4 v4 = *(const float4*)(xb + (size_t)cr * HW_ + p0 + pc);
    u16* d = &xs[cr * 128 + pc];
    d[0] = f2bf(v4.x); d[1] = f2bf(v4.y); d[2] = f2bf(v4.z); d[3] = f2bf(v4.w);
  }
  __syncthreads();

  const int oy = tid >> 5, px = tid & 31;
  float acc[8][4];
  #pragma unroll
  for (int i = 0; i < 8; ++i)
    #pragma unroll
    for (int j = 0; j < 4; ++j) acc[i][j] = 0.f;

  for (int c = 0; c < 128; ++c) {
    u32 a4[4];
    *(uint4*)a4 = *(const uint4*)&wsT[c * 72 + oy * 8];
    float a[8];
    #pragma unroll
    for (int t = 0; t < 4; ++t) { a[2 * t] = bflo(a4[t]); a[2 * t + 1] = bfhi(a4[t]); }
    float bx[4];
    #pragma unroll
    for (int j = 0; j < 4; ++j) bx[j] = bf2f_u(xs[c * 128 + px + j * 32]);
    #pragma unroll
    for (int i = 0; i < 8; ++i)
      #pragma unroll
      for (int j = 0; j < 4; ++j) acc[i][j] += a[i] * bx[j];
  }

  float* ob = out + (size_t)b * (C_ * HW_);
  #pragma unroll
  for (int i = 0; i < 8; ++i)
    #pragma unroll
    for (int j = 0; j < 4; ++j)
      ob[(size_t)(o0 + oy * 8 + i) * HW_ + p0 + px + j * 32] = acc[i][j];
}

// ---------------------------------------------------------------------------
extern "C" void kernel_launch(void* const* d_in, const int* in_sizes, int n_in,
                              void* d_out, int out_size, void* d_ws, size_t ws_size,
                              hipStream_t stream) {
  const float* x     = (const float*)d_in[0];
  const float* wqkv  = (const float*)d_in[1];
  const float* wproj = (const float*)d_in[2];
  const float* wdw   = (const float*)d_in[3];
  const float* gamma = (const float*)d_in[4];
  float* out = (float*)d_out;
  char* ws = (char*)d_ws;

  // workspace layout (224 MB total)
  u16*   q  = (u16*)(ws);                    // 32 MB  [B,4,HW,32] bf16
  u16*   k  = (u16*)(ws + 33554432ull);      // 32 MB
  u16*   v  = (u16*)(ws + 67108864ull);      // 32 MB
  u16*   hb = (u16*)(ws + 100663296ull);     // 32 MB  [B,C,H,W] bf16
  u16*   wb = (u16*)(ws + 134217728ull);     // 32 MB  [B,C,W,H] bf16
  float* cv = (float*)(ws + 167772160ull);   // 64 MB  [B,C,HW] f32

  k_qkv <<<dim3(128, 6, 8), 256, 0, stream>>>(x, wqkv, q);
  k_attn<<<dim3(128, 4, 8), 256, 0, stream>>>(q, k, v, gamma, hb, 0);
  k_attn<<<dim3(128, 4, 8), 256, 0, stream>>>(q, k, v, gamma, wb, 1);
  k_conv<<<dim3(128, 8),    256, 0, stream>>>(hb, wb, wdw, cv);
  k_proj<<<dim3(128, 2, 8), 256, 0, stream>>>(cv, wproj, out);
}

// Round 2
// 571.712 us; speedup vs baseline: 1.6599x; 1.6599x over previous
//
#include <hip/hip_runtime.h>

typedef unsigned short u16;
typedef unsigned int   u32;
typedef short bf16x8 __attribute__((ext_vector_type(8)));
typedef float f32x4  __attribute__((ext_vector_type(4)));

#define B_   8
#define C_   128
#define H_   128
#define W_   128
#define NH   4
#define D_   32
#define HW_  16384
#define SCALE 0.17677669529663687f

__device__ __forceinline__ float bf2f_u(u16 u) { union { u32 i; float f; } x; x.i = ((u32)u) << 16; return x.f; }
__device__ __forceinline__ float bflo(u32 u)   { union { u32 i; float f; } x; x.i = u << 16; return x.f; }
__device__ __forceinline__ float bfhi(u32 u)   { union { u32 i; float f; } x; x.i = u & 0xffff0000u; return x.f; }
__device__ __forceinline__ u16   f2bf(float f) {
  union { float f; u32 i; } x; x.f = f;
  u32 i = x.i;
  return (u16)((i + 0x7fffu + ((i >> 16) & 1u)) >> 16);
}

__device__ __forceinline__ bf16x8 ld_frag_g(const u16* p) {
  union { uint4 u; bf16x8 f; } c; c.u = *(const uint4*)p; return c.f;
}

// ---------------------------------------------------------------------------
// K1: qkv 1x1 conv (GEMM). x:[B,C,HW] f32, wqkv:[384,128] f32
// -> q/k/v bf16, each laid out [B, head, pixel, dim] (dim=32 contiguous)
// ---------------------------------------------------------------------------
__global__ __launch_bounds__(256) void k_qkv(const float* __restrict__ x,
                                             const float* __restrict__ wqkv,
                                             u16* __restrict__ qkvb) {
  __shared__ u16 xs[128 * 128];
  __shared__ u16 wsT[128 * 72];
  const int tid = threadIdx.x;
  const int p0 = blockIdx.x * 128;
  const int o0 = blockIdx.y * 64;
  const int b  = blockIdx.z;
  const float* xb = x + (size_t)b * (C_ * HW_);

  for (int i = tid; i < 64 * 128; i += 256) {
    int o = i >> 7, cc = i & 127;
    wsT[cc * 72 + o] = f2bf(wqkv[(o0 + o) * 128 + cc]);
  }
  for (int i = tid; i < 128 * 32; i += 256) {
    int cr = i >> 5, pc = (i & 31) * 4;
    float4 v4 = *(const float4*)(xb + (size_t)cr * HW_ + p0 + pc);
    u16* d = &xs[cr * 128 + pc];
    d[0] = f2bf(v4.x); d[1] = f2bf(v4.y); d[2] = f2bf(v4.z); d[3] = f2bf(v4.w);
  }
  __syncthreads();

  const int oy = tid >> 5, px = tid & 31;
  float acc[8][4];
  #pragma unroll
  for (int i = 0; i < 8; ++i)
    #pragma unroll
    for (int j = 0; j < 4; ++j) acc[i][j] = 0.f;

  for (int c = 0; c < 128; ++c) {
    u32 a4[4];
    *(uint4*)a4 = *(const uint4*)&wsT[c * 72 + oy * 8];
    float a[8];
    #pragma unroll
    for (int t = 0; t < 4; ++t) { a[2 * t] = bflo(a4[t]); a[2 * t + 1] = bfhi(a4[t]); }
    float bx[4];
    #pragma unroll
    for (int j = 0; j < 4; ++j) bx[j] = bf2f_u(xs[c * 128 + px + j * 32]);
    #pragma unroll
    for (int i = 0; i < 8; ++i)
      #pragma unroll
      for (int j = 0; j < 4; ++j) acc[i][j] += a[i] * bx[j];
  }
  __syncthreads();

  u16* ldsT = xs;
  #pragma unroll
  for (int i = 0; i < 8; ++i)
    #pragma unroll
    for (int j = 0; j < 4; ++j)
      ldsT[(px + j * 32) * 72 + oy * 8 + i] = f2bf(acc[i][j]);
  __syncthreads();

  const int sel   = o0 >> 7;
  const int headb = (o0 & 127) >> 5;
  u16* ob = qkvb + (size_t)sel * ((size_t)B_ * NH * HW_ * D_);
  for (int ci = tid; ci < 1024; ci += 256) {
    int ho = ci >> 9, cc = ci & 511;
    int p = cc >> 2, quad = cc & 3;
    uint4 val = *(const uint4*)&ldsT[p * 72 + ho * 32 + quad * 8];
    size_t doff = ((size_t)((b * NH + headb + ho) * HW_ + p0 + p)) * D_ + quad * 8;
    *(uint4*)(ob + doff) = val;
  }
}

// ---------------------------------------------------------------------------
// K2: MFMA flash attention, wave-per-line, both axes in one launch.
// block = 256 threads = 4 waves = 4 lines. blockIdx.y = head + 4*axis.
// Q/K A/B-frags straight from global; V transposed to wave-private LDS;
// P round-trips through wave-private LDS (pair-packed dwords, stride 68).
// No __syncthreads anywhere (all LDS is wave-private, DS is in-order).
// ---------------------------------------------------------------------------
__global__ __launch_bounds__(256) void k_attn_mfma(const u16* __restrict__ qb,
                                                   const u16* __restrict__ kb,
                                                   const u16* __restrict__ vb,
                                                   const float* __restrict__ gp,
                                                   u16* __restrict__ houtb,
                                                   u16* __restrict__ woutb) {
  // per wave: vt[32][68] dwords (V^T pair-packed), pt[16][68] dwords (P tile)
  __shared__ u32 lds[4][32 * 68 + 16 * 68];
  const int tid  = threadIdx.x;
  const int w    = tid >> 6;
  const int lane = tid & 63;
  const int head = blockIdx.y & 3;
  const int axis = blockIdx.y >> 2;
  const int b    = blockIdx.z;
  const int line = blockIdx.x * 4 + w;
  u32* vt = &lds[w][0];
  u32* pt = &lds[w][32 * 68];
  const size_t base = (size_t)(b * NH + head) * HW_ * D_;
  const float g = gp[0];
  const int c16 = lane & 15, rg = lane >> 4;
  // pixel strides: elem(p) = base + pix(p)*32;  pix = axis ? p*128+line : line*128+p
  const size_t pstride = axis ? (size_t)128 * D_ : (size_t)D_;
  const size_t lbase   = base + (size_t)line * (axis ? D_ : 128 * D_);

  // ---- stage V^T (pair-packed along z) ----
  {
    const u16* v0p = vb + lbase + (size_t)(2 * lane) * pstride;
    const u16* v1p = v0p + pstride;
    u32 v0r[16], v1r[16];
    #pragma unroll
    for (int t = 0; t < 4; ++t) {
      *(uint4*)&v0r[4 * t] = *(const uint4*)(v0p + 8 * t);
      *(uint4*)&v1r[4 * t] = *(const uint4*)(v1p + 8 * t);
    }
    #pragma unroll
    for (int dw = 0; dw < 16; ++dw) {
      u32 a = v0r[dw], bq = v1r[dw];
      u32 lo = (a & 0xffffu) | (bq << 16);
      u32 hi = (a >> 16) | (bq & 0xffff0000u);
      vt[(2 * dw) * 68 + lane]     = lo;
      vt[(2 * dw + 1) * 68 + lane] = hi;
    }
  }

  // ---- K B-frags from global (resident) ----
  bf16x8 kf[8];
  #pragma unroll
  for (int nt = 0; nt < 8; ++nt)
    kf[nt] = ld_frag_g(kb + lbase + (size_t)(nt * 16 + c16) * pstride + rg * 8);

  // ---- V^T B-frags from LDS (resident) ----
  bf16x8 vf[2][4];
  #pragma unroll
  for (int ntd = 0; ntd < 2; ++ntd)
    #pragma unroll
    for (int t = 0; t < 4; ++t) {
      union { uint4 u; bf16x8 f; } c;
      c.u = *(const uint4*)(vt + (ntd * 16 + c16) * 68 + t * 16 + rg * 4);
      vf[ntd][t] = c.f;
    }

  // ---- decay running products: F = exp(-g*(z-j)), Fi = exp(+g*(z-j)) ----
  const float R16 = __expf(-16.f * g), Ri16 = __expf(16.f * g);
  const float R144 = __expf(-144.f * g), Ri144 = __expf(144.f * g);
  float F[4], Fi[4];
  #pragma unroll
  for (int r = 0; r < 4; ++r) {
    float t0 = (float)(c16 - (rg * 4 + r));
    F[r]  = __expf(-g * t0);
    Fi[r] = __expf(g * t0);
  }

  u16* ob = axis ? woutb : houtb;
  const f32x4 zero = {0.f, 0.f, 0.f, 0.f};

  #pragma unroll 1
  for (int mt = 0; mt < 8; ++mt) {
    // Q A-frag straight from global
    bf16x8 qf = ld_frag_g(qb + lbase + (size_t)(mt * 16 + c16) * pstride + rg * 8);

    f32x4 sa[8];
    #pragma unroll
    for (int nt = 0; nt < 8; ++nt)
      sa[nt] = __builtin_amdgcn_mfma_f32_16x16x32_bf16(qf, kf[nt], zero, 0, 0, 0);

    // softmax rows j = mt*16 + rg*4 + r (cols z = nt*16 + c16), then *decay/l,
    // pack pairs (z even|odd) via lane^1 and write P-tile to pt[m][zp]
    #pragma unroll
    for (int r = 0; r < 4; ++r) {
      float mx = sa[0][r];
      #pragma unroll
      for (int nt = 1; nt < 8; ++nt) mx = fmaxf(mx, sa[nt][r]);
      mx = fmaxf(mx, __shfl_xor(mx, 1));
      mx = fmaxf(mx, __shfl_xor(mx, 2));
      mx = fmaxf(mx, __shfl_xor(mx, 4));
      mx = fmaxf(mx, __shfl_xor(mx, 8));
      const float msc = mx * SCALE;
      float l = 0.f;
      #pragma unroll
      for (int nt = 0; nt < 8; ++nt) {
        float e = __expf(sa[nt][r] * SCALE - msc);
        l += e;
        sa[nt][r] = e;
      }
      l += __shfl_xor(l, 1);
      l += __shfl_xor(l, 2);
      l += __shfl_xor(l, 4);
      l += __shfl_xor(l, 8);
      const float li = __builtin_amdgcn_rcpf(l);
      float f = F[r], fi = Fi[r];
      #pragma unroll
      for (int nt = 0; nt < 8; ++nt) {
        float pv = sa[nt][r] * (li * fminf(f, fi));
        f *= R16; fi *= Ri16;
        union { float f; u32 i; } cu; cu.f = pv;
        u32 u = (cu.i + 0x8000u) >> 16;
        u32 uo = (u32)__shfl_xor((int)u, 1);
        u32 dwv = (u & 0xffffu) | (uo << 16);
        if (!(lane & 1)) pt[(rg * 4 + r) * 68 + nt * 8 + (c16 >> 1)] = dwv;
      }
      F[r] = f * Ri144;   // advance: z rewinds -128, j += 16
      Fi[r] = fi * R144;
    }

    // PV: A-frags from pt, B = resident V^T frags
    f32x4 oa0 = zero, oa1 = zero;
    #pragma unroll
    for (int t = 0; t < 4; ++t) {
      union { uint4 u; bf16x8 f; } af;
      af.u = *(const uint4*)(pt + c16 * 68 + t * 16 + rg * 4);
      oa0 = __builtin_amdgcn_mfma_f32_16x16x32_bf16(af.f, vf[0][t], oa0, 0, 0, 0);
      oa1 = __builtin_amdgcn_mfma_f32_16x16x32_bf16(af.f, vf[1][t], oa1, 0, 0, 0);
    }

    // store out tile: rows j = mt*16+rg*4+r (4 consecutive -> 1 dwordx2), col d
    #pragma unroll
    for (int ntd = 0; ntd < 2; ++ntd) {
      f32x4 oa = ntd ? oa1 : oa0;
      u32 lo = (u32)f2bf(oa[0]) | ((u32)f2bf(oa[1]) << 16);
      u32 hi = (u32)f2bf(oa[2]) | ((u32)f2bf(oa[3]) << 16);
      int d = ntd * 16 + c16;
      size_t off = ((size_t)((b * C_ + head * D_ + d) * 128 + line)) * 128 + mt * 16 + rg * 4;
      uint2 st; st.x = lo; st.y = hi;
      *(uint2*)(ob + off) = st;
    }
  }
}

// ---------------------------------------------------------------------------
// K4: combine out_h + out_w^T, then depthwise 3x3 SAME conv, per (b,c) plane
// ---------------------------------------------------------------------------
__global__ __launch_bounds__(256) void k_conv(const u16* __restrict__ hb,
                                              const u16* __restrict__ wb,
                                              const float* __restrict__ wdw,
                                              float* __restrict__ convo) {
  __shared__ u16 t[128 * 136];
  const int tid = threadIdx.x;
  const int c = blockIdx.x, b = blockIdx.y;
  const size_t pb = (size_t)(b * C_ + c) * HW_;

  for (int i = tid; i < 2048; i += 256) {
    int e = i * 8; int r = e >> 7, col = e & 127;
    *(uint4*)&t[r * 136 + col] = *(const uint4*)(hb + pb + e);
  }
  __syncthreads();
  for (int i = tid; i < 4096; i += 256) {
    int e = i * 4; int wr = e >> 7, hc = e & 127;
    u32 u2[2]; *(uint2*)u2 = *(const uint2*)(wb + pb + e);
    float f0 = bflo(u2[0]), f1 = bfhi(u2[0]), f2v = bflo(u2[1]), f3 = bfhi(u2[1]);
    t[(hc + 0) * 136 + wr] = f2bf(bf2f_u(t[(hc + 0) * 136 + wr]) + f0);
    t[(hc + 1) * 136 + wr] = f2bf(bf2f_u(t[(hc + 1) * 136 + wr]) + f1);
    t[(hc + 2) * 136 + wr] = f2bf(bf2f_u(t[(hc + 2) * 136 + wr]) + f2v);
    t[(hc + 3) * 136 + wr] = f2bf(bf2f_u(t[(hc + 3) * 136 + wr]) + f3);
  }
  __syncthreads();

  float k9[9];
  #pragma unroll
  for (int i = 0; i < 9; ++i) k9[i] = wdw[c * 9 + i];

  for (int px = tid; px < HW_; px += 256) {
    int r = px >> 7, col = px & 127;
    float a = 0.f;
    #pragma unroll
    for (int di = 0; di < 3; ++di) {
      int rr = r + di - 1;
      if (rr < 0 || rr > 127) continue;
      #pragma unroll
      for (int dj = 0; dj < 3; ++dj) {
        int cc2 = col + dj - 1;
        if (cc2 < 0 || cc2 > 127) continue;
        a += k9[di * 3 + dj] * bf2f_u(t[rr * 136 + cc2]);
      }
    }
    convo[pb + px] = a;
  }
}

// ---------------------------------------------------------------------------
// K5: proj 1x1 conv (GEMM) -> d_out f32 NCHW
// ---------------------------------------------------------------------------
__global__ __launch_bounds__(256) void k_proj(const float* __restrict__ cin,
                                              const float* __restrict__ wp,
                                              float* __restrict__ out) {
  __shared__ u16 xs[128 * 128];
  __shared__ u16 wsT[128 * 72];
  const int tid = threadIdx.x;
  const int p0 = blockIdx.x * 128;
  const int o0 = blockIdx.y * 64;
  const int b  = blockIdx.z;
  const float* xb = cin + (size_t)b * (C_ * HW_);

  for (int i = tid; i < 64 * 128; i += 256) {
    int o = i >> 7, cc = i & 127;
    wsT[cc * 72 + o] = f2bf(wp[(o0 + o) * 128 + cc]);
  }
  for (int i = tid; i < 128 * 32; i += 256) {
    int cr = i >> 5, pc = (i & 31) * 4;
    float4 v4 = *(const float4*)(xb + (size_t)cr * HW_ + p0 + pc);
    u16* d = &xs[cr * 128 + pc];
    d[0] = f2bf(v4.x); d[1] = f2bf(v4.y); d[2] = f2bf(v4.z); d[3] = f2bf(v4.w);
  }
  __syncthreads();

  const int oy = tid >> 5, px = tid & 31;
  float acc[8][4];
  #pragma unroll
  for (int i = 0; i < 8; ++i)
    #pragma unroll
    for (int j = 0; j < 4; ++j) acc[i][j] = 0.f;

  for (int c = 0; c < 128; ++c) {
    u32 a4[4];
    *(uint4*)a4 = *(const uint4*)&wsT[c * 72 + oy * 8];
    float a[8];
    #pragma unroll
    for (int t = 0; t < 4; ++t) { a[2 * t] = bflo(a4[t]); a[2 * t + 1] = bfhi(a4[t]); }
    float bx[4];
    #pragma unroll
    for (int j = 0; j < 4; ++j) bx[j] = bf2f_u(xs[c * 128 + px + j * 32]);
    #pragma unroll
    for (int i = 0; i < 8; ++i)
      #pragma unroll
      for (int j = 0; j < 4; ++j) acc[i][j] += a[i] * bx[j];
  }

  float* ob = out + (size_t)b * (C_ * HW_);
  #pragma unroll
  for (int i = 0; i < 8; ++i)
    #pragma unroll
    for (int j = 0; j < 4; ++j)
      ob[(size_t)(o0 + oy * 8 + i) * HW_ + p0 + px + j * 32] = acc[i][j];
}

// ---------------------------------------------------------------------------
extern "C" void kernel_launch(void* const* d_in, const int* in_sizes, int n_in,
                              void* d_out, int out_size, void* d_ws, size_t ws_size,
                              hipStream_t stream) {
  const float* x     = (const float*)d_in[0];
  const float* wqkv  = (const float*)d_in[1];
  const float* wproj = (const float*)d_in[2];
  const float* wdw   = (const float*)d_in[3];
  const float* gamma = (const float*)d_in[4];
  float* out = (float*)d_out;
  char* ws = (char*)d_ws;

  u16*   q  = (u16*)(ws);                    // 32 MB  [B,4,HW,32] bf16
  u16*   k  = (u16*)(ws + 33554432ull);      // 32 MB
  u16*   v  = (u16*)(ws + 67108864ull);      // 32 MB
  u16*   hb = (u16*)(ws + 100663296ull);     // 32 MB  [B,C,H,W] bf16
  u16*   wb = (u16*)(ws + 134217728ull);     // 32 MB  [B,C,W,H] bf16
  float* cv = (float*)(ws + 167772160ull);   // 64 MB  [B,C,HW] f32

  k_qkv     <<<dim3(128, 6, 8), 256, 0, stream>>>(x, wqkv, q);
  k_attn_mfma<<<dim3(32, 8, 8), 256, 0, stream>>>(q, k, v, gamma, hb, wb);
  k_conv    <<<dim3(128, 8),    256, 0, stream>>>(hb, wb, wdw, cv);
  k_proj    <<<dim3(128, 2, 8), 256, 0, stream>>>(cv, wproj, out);
}

// Round 3
// 405.301 us; speedup vs baseline: 2.3415x; 1.4106x over previous
//
#include <hip/hip_runtime.h>

typedef unsigned short u16;
typedef unsigned int   u32;
typedef short bf16x8 __attribute__((ext_vector_type(8)));
typedef float f32x4  __attribute__((ext_vector_type(4)));

#define B_   8
#define C_   128
#define H_   128
#define W_   128
#define NH   4
#define D_   32
#define HW_  16384
#define SCALE 0.17677669529663687f

__device__ __forceinline__ float bf2f_u(u16 u) { union { u32 i; float f; } x; x.i = ((u32)u) << 16; return x.f; }
__device__ __forceinline__ float bflo(u32 u)   { union { u32 i; float f; } x; x.i = u << 16; return x.f; }
__device__ __forceinline__ float bfhi(u32 u)   { union { u32 i; float f; } x; x.i = u & 0xffff0000u; return x.f; }
__device__ __forceinline__ u16   f2bf(float f) {
  union { float f; u32 i; } x; x.f = f;
  u32 i = x.i;
  return (u16)((i + 0x7fffu + ((i >> 16) & 1u)) >> 16);
}
__device__ __forceinline__ u32 pk2(float a, float b) {
  return (u32)f2bf(a) | ((u32)f2bf(b) << 16);
}
__device__ __forceinline__ bf16x8 ld_frag_g(const u16* p) {
  union { uint4 u; bf16x8 f; } c; c.u = *(const uint4*)p; return c.f;
}

// ---------------------------------------------------------------------------
// k_wcvt: f32 weights -> bf16, row-major preserved. n4 = count of float4s.
// ---------------------------------------------------------------------------
__global__ __launch_bounds__(256) void k_wcvt(const float* __restrict__ src,
                                              u16* __restrict__ dst, int n4) {
  int i = blockIdx.x * 256 + threadIdx.x;
  if (i < n4) {
    float4 v = ((const float4*)src)[i];
    uint2 st; st.x = pk2(v.x, v.y); st.y = pk2(v.z, v.w);
    *(uint2*)(dst + (size_t)i * 4) = st;
  }
}

// ---------------------------------------------------------------------------
// t_f32: x [b][c][p] f32 -> xT [b][p][c] bf16. Block: 128 pixels, full C=128.
// LDS rows stride 65 dwords (odd): writes/reads land 2-way max (free).
// ---------------------------------------------------------------------------
__global__ __launch_bounds__(256) void t_f32(const float* __restrict__ src,
                                             u16* __restrict__ dst) {
  __shared__ u32 tile[128 * 65];
  const int tid = threadIdx.x, w = tid >> 6, lane = tid & 63;
  const int b = blockIdx.z;
  const int P0 = blockIdx.x * 128;
  const float* sb = src + (size_t)b * C_ * HW_ + P0;

  #pragma unroll
  for (int ci = 0; ci < 4; ++ci) {
    int cp = 16 * w + 4 * ci + (lane >> 4);      // c-pair 0..63
    #pragma unroll
    for (int ph = 0; ph < 2; ++ph) {
      int p = 4 * (lane & 15) + 64 * ph;
      const float* r0 = sb + (size_t)(2 * cp) * HW_ + p;
      float4 a  = *(const float4*)r0;
      float4 bb = *(const float4*)(r0 + HW_);
      tile[(p + 0) * 65 + cp] = pk2(a.x, bb.x);
      tile[(p + 1) * 65 + cp] = pk2(a.y, bb.y);
      tile[(p + 2) * 65 + cp] = pk2(a.z, bb.z);
      tile[(p + 3) * 65 + cp] = pk2(a.w, bb.w);
    }
  }
  __syncthreads();
  u32* db = (u32*)(dst + ((size_t)b * HW_ + P0) * 128);
  #pragma unroll
  for (int it = 0; it < 8; ++it) {
    int p  = (tid >> 4) + 16 * it;
    int dq = (tid & 15) * 4;
    uint4 v;
    v.x = tile[p * 65 + dq];     v.y = tile[p * 65 + dq + 1];
    v.z = tile[p * 65 + dq + 2]; v.w = tile[p * 65 + dq + 3];
    *(uint4*)(db + p * 64 + dq) = v;
  }
}

// ---------------------------------------------------------------------------
// t_bf16: cv [b][c][p] bf16 -> cvT [b][p][c] bf16. Same scheme.
// ---------------------------------------------------------------------------
__global__ __launch_bounds__(256) void t_bf16(const u16* __restrict__ src,
                                              u16* __restrict__ dst) {
  __shared__ u32 tile[128 * 65];
  const int tid = threadIdx.x, w = tid >> 6, lane = tid & 63;
  const int b = blockIdx.z;
  const int P0 = blockIdx.x * 128;
  const u16* sb = src + (size_t)b * C_ * HW_ + P0;

  #pragma unroll
  for (int ci = 0; ci < 4; ++ci) {
    int cp = 16 * w + 4 * ci + (lane >> 4);
    #pragma unroll
    for (int ph = 0; ph < 2; ++ph) {
      int p = 4 * (lane & 15) + 64 * ph;
      const u16* r0 = sb + (size_t)(2 * cp) * HW_ + p;
      uint2 a  = *(const uint2*)r0;
      uint2 bb = *(const uint2*)(r0 + HW_);
      tile[(p + 0) * 65 + cp] = (a.x & 0xffffu) | (bb.x << 16);
      tile[(p + 1) * 65 + cp] = (a.x >> 16)     | (bb.x & 0xffff0000u);
      tile[(p + 2) * 65 + cp] = (a.y & 0xffffu) | (bb.y << 16);
      tile[(p + 3) * 65 + cp] = (a.y >> 16)     | (bb.y & 0xffff0000u);
    }
  }
  __syncthreads();
  u32* db = (u32*)(dst + ((size_t)b * HW_ + P0) * 128);
  #pragma unroll
  for (int it = 0; it < 8; ++it) {
    int p  = (tid >> 4) + 16 * it;
    int dq = (tid & 15) * 4;
    uint4 v;
    v.x = tile[p * 65 + dq];     v.y = tile[p * 65 + dq + 1];
    v.z = tile[p * 65 + dq + 2]; v.w = tile[p * 65 + dq + 3];
    *(uint4*)(db + p * 64 + dq) = v;
  }
}

// ---------------------------------------------------------------------------
// k_qkv: streaming MFMA GEMM. xT [b][p][128c] bf16, wqb [384][128] bf16.
// Per wave: 32 pixels resident as B-frags; 3 passes (q,k,v) x M=128.
// No LDS, no syncthreads. Output [b][head][pix][d] bf16.
// ---------------------------------------------------------------------------
__global__ __launch_bounds__(256) void k_qkv(const u16* __restrict__ xT,
                                             const u16* __restrict__ wqb,
                                             u16* __restrict__ qkvb) {
  const int tid = threadIdx.x, w = tid >> 6, lane = tid & 63;
  const int c16 = lane & 15, rg = lane >> 4;
  const int b = blockIdx.z;
  const int p0 = blockIdx.x * 128 + w * 32;
  const u16* xb = xT + ((size_t)b * HW_ + p0) * 128;

  bf16x8 bfr[2][4];
  #pragma unroll
  for (int nt = 0; nt < 2; ++nt)
    #pragma unroll
    for (int kk = 0; kk < 4; ++kk)
      bfr[nt][kk] = ld_frag_g(xb + (size_t)(nt * 16 + c16) * 128 + kk * 32 + rg * 8);

  const f32x4 zero = {0.f, 0.f, 0.f, 0.f};
  #pragma unroll 1
  for (int pass = 0; pass < 3; ++pass) {
    f32x4 acc[8][2];
    #pragma unroll
    for (int mt = 0; mt < 8; ++mt) { acc[mt][0] = zero; acc[mt][1] = zero; }

    #pragma unroll
    for (int kk = 0; kk < 4; ++kk) {
      #pragma unroll
      for (int mt = 0; mt < 8; ++mt) {
        bf16x8 af = ld_frag_g(wqb + (size_t)(pass * 128 + mt * 16 + c16) * 128 + kk * 32 + rg * 8);
        acc[mt][0] = __builtin_amdgcn_mfma_f32_16x16x32_bf16(af, bfr[0][kk], acc[mt][0], 0, 0, 0);
        acc[mt][1] = __builtin_amdgcn_mfma_f32_16x16x32_bf16(af, bfr[1][kk], acc[mt][1], 0, 0, 0);
      }
    }

    u16* ob = qkvb + (size_t)pass * ((size_t)B_ * NH * HW_ * D_);
    #pragma unroll
    for (int mt = 0; mt < 8; ++mt) {
      int head = mt >> 1, d0 = (mt & 1) * 16 + rg * 4;
      #pragma unroll
      for (int nt = 0; nt < 2; ++nt) {
        f32x4 oa = acc[mt][nt];
        uint2 st;
        st.x = pk2(oa[0], oa[1]);
        st.y = pk2(oa[2], oa[3]);
        int pix = p0 + nt * 16 + c16;
        *(uint2*)(ob + ((size_t)(b * NH + head) * HW_ + pix) * 32 + d0) = st;
      }
    }
  }
}

// ---------------------------------------------------------------------------
// k_proj: streaming MFMA GEMM. cvT [b][p][128c] bf16, wpb [128][128] bf16.
// Output f32 NCHW (d_out).
// ---------------------------------------------------------------------------
__global__ __launch_bounds__(256) void k_proj(const u16* __restrict__ cvT,
                                              const u16* __restrict__ wpb,
                                              float* __restrict__ out) {
  const int tid = threadIdx.x, w = tid >> 6, lane = tid & 63;
  const int c16 = lane & 15, rg = lane >> 4;
  const int b = blockIdx.z;
  const int p0 = blockIdx.x * 128 + w * 32;
  const u16* xb = cvT + ((size_t)b * HW_ + p0) * 128;

  bf16x8 bfr[2][4];
  #pragma unroll
  for (int nt = 0; nt < 2; ++nt)
    #pragma unroll
    for (int kk = 0; kk < 4; ++kk)
      bfr[nt][kk] = ld_frag_g(xb + (size_t)(nt * 16 + c16) * 128 + kk * 32 + rg * 8);

  const f32x4 zero = {0.f, 0.f, 0.f, 0.f};
  f32x4 acc[8][2];
  #pragma unroll
  for (int mt = 0; mt < 8; ++mt) { acc[mt][0] = zero; acc[mt][1] = zero; }

  #pragma unroll
  for (int kk = 0; kk < 4; ++kk) {
    #pragma unroll
    for (int mt = 0; mt < 8; ++mt) {
      bf16x8 af = ld_frag_g(wpb + (size_t)(mt * 16 + c16) * 128 + kk * 32 + rg * 8);
      acc[mt][0] = __builtin_amdgcn_mfma_f32_16x16x32_bf16(af, bfr[0][kk], acc[mt][0], 0, 0, 0);
      acc[mt][1] = __builtin_amdgcn_mfma_f32_16x16x32_bf16(af, bfr[1][kk], acc[mt][1], 0, 0, 0);
    }
  }

  float* ob = out + (size_t)b * C_ * HW_;
  #pragma unroll
  for (int mt = 0; mt < 8; ++mt) {
    #pragma unroll
    for (int nt = 0; nt < 2; ++nt) {
      f32x4 oa = acc[mt][nt];
      int pix = p0 + nt * 16 + c16;
      #pragma unroll
      for (int r = 0; r < 4; ++r) {
        int o = mt * 16 + rg * 4 + r;
        ob[(size_t)o * HW_ + pix] = oa[r];
      }
    }
  }
}

// ---------------------------------------------------------------------------
// k_attn_mfma: unchanged from R2 (passed, fast).
// ---------------------------------------------------------------------------
__global__ __launch_bounds__(256) void k_attn_mfma(const u16* __restrict__ qb,
                                                   const u16* __restrict__ kb,
                                                   const u16* __restrict__ vb,
                                                   const float* __restrict__ gp,
                                                   u16* __restrict__ houtb,
                                                   u16* __restrict__ woutb) {
  __shared__ u32 lds[4][32 * 68 + 16 * 68];
  const int tid  = threadIdx.x;
  const int w    = tid >> 6;
  const int lane = tid & 63;
  const int head = blockIdx.y & 3;
  const int axis = blockIdx.y >> 2;
  const int b    = blockIdx.z;
  const int line = blockIdx.x * 4 + w;
  u32* vt = &lds[w][0];
  u32* pt = &lds[w][32 * 68];
  const size_t base = (size_t)(b * NH + head) * HW_ * D_;
  const float g = gp[0];
  const int c16 = lane & 15, rg = lane >> 4;
  const size_t pstride = axis ? (size_t)128 * D_ : (size_t)D_;
  const size_t lbase   = base + (size_t)line * (axis ? D_ : 128 * D_);

  {
    const u16* v0p = vb + lbase + (size_t)(2 * lane) * pstride;
    const u16* v1p = v0p + pstride;
    u32 v0r[16], v1r[16];
    #pragma unroll
    for (int t = 0; t < 4; ++t) {
      *(uint4*)&v0r[4 * t] = *(const uint4*)(v0p + 8 * t);
      *(uint4*)&v1r[4 * t] = *(const uint4*)(v1p + 8 * t);
    }
    #pragma unroll
    for (int dw = 0; dw < 16; ++dw) {
      u32 a = v0r[dw], bq = v1r[dw];
      u32 lo = (a & 0xffffu) | (bq << 16);
      u32 hi = (a >> 16) | (bq & 0xffff0000u);
      vt[(2 * dw) * 68 + lane]     = lo;
      vt[(2 * dw + 1) * 68 + lane] = hi;
    }
  }

  bf16x8 kf[8];
  #pragma unroll
  for (int nt = 0; nt < 8; ++nt)
    kf[nt] = ld_frag_g(kb + lbase + (size_t)(nt * 16 + c16) * pstride + rg * 8);

  bf16x8 vf[2][4];
  #pragma unroll
  for (int ntd = 0; ntd < 2; ++ntd)
    #pragma unroll
    for (int t = 0; t < 4; ++t) {
      union { uint4 u; bf16x8 f; } c;
      c.u = *(const uint4*)(vt + (ntd * 16 + c16) * 68 + t * 16 + rg * 4);
      vf[ntd][t] = c.f;
    }

  const float R16 = __expf(-16.f * g), Ri16 = __expf(16.f * g);
  const float R144 = __expf(-144.f * g), Ri144 = __expf(144.f * g);
  float F[4], Fi[4];
  #pragma unroll
  for (int r = 0; r < 4; ++r) {
    float t0 = (float)(c16 - (rg * 4 + r));
    F[r]  = __expf(-g * t0);
    Fi[r] = __expf(g * t0);
  }

  u16* ob = axis ? woutb : houtb;
  const f32x4 zero = {0.f, 0.f, 0.f, 0.f};

  #pragma unroll 1
  for (int mt = 0; mt < 8; ++mt) {
    bf16x8 qf = ld_frag_g(qb + lbase + (size_t)(mt * 16 + c16) * pstride + rg * 8);

    f32x4 sa[8];
    #pragma unroll
    for (int nt = 0; nt < 8; ++nt)
      sa[nt] = __builtin_amdgcn_mfma_f32_16x16x32_bf16(qf, kf[nt], zero, 0, 0, 0);

    #pragma unroll
    for (int r = 0; r < 4; ++r) {
      float mx = sa[0][r];
      #pragma unroll
      for (int nt = 1; nt < 8; ++nt) mx = fmaxf(mx, sa[nt][r]);
      mx = fmaxf(mx, __shfl_xor(mx, 1));
      mx = fmaxf(mx, __shfl_xor(mx, 2));
      mx = fmaxf(mx, __shfl_xor(mx, 4));
      mx = fmaxf(mx, __shfl_xor(mx, 8));
      const float msc = mx * SCALE;
      float l = 0.f;
      #pragma unroll
      for (int nt = 0; nt < 8; ++nt) {
        float e = __expf(sa[nt][r] * SCALE - msc);
        l += e;
        sa[nt][r] = e;
      }
      l += __shfl_xor(l, 1);
      l += __shfl_xor(l, 2);
      l += __shfl_xor(l, 4);
      l += __shfl_xor(l, 8);
      const float li = __builtin_amdgcn_rcpf(l);
      float f = F[r], fi = Fi[r];
      #pragma unroll
      for (int nt = 0; nt < 8; ++nt) {
        float pv = sa[nt][r] * (li * fminf(f, fi));
        f *= R16; fi *= Ri16;
        union { float f; u32 i; } cu; cu.f = pv;
        u32 u = (cu.i + 0x8000u) >> 16;
        u32 uo = (u32)__shfl_xor((int)u, 1);
        u32 dwv = (u & 0xffffu) | (uo << 16);
        if (!(lane & 1)) pt[(rg * 4 + r) * 68 + nt * 8 + (c16 >> 1)] = dwv;
      }
      F[r] = f * Ri144;
      Fi[r] = fi * R144;
    }

    f32x4 oa0 = zero, oa1 = zero;
    #pragma unroll
    for (int t = 0; t < 4; ++t) {
      union { uint4 u; bf16x8 f; } af;
      af.u = *(const uint4*)(pt + c16 * 68 + t * 16 + rg * 4);
      oa0 = __builtin_amdgcn_mfma_f32_16x16x32_bf16(af.f, vf[0][t], oa0, 0, 0, 0);
      oa1 = __builtin_amdgcn_mfma_f32_16x16x32_bf16(af.f, vf[1][t], oa1, 0, 0, 0);
    }

    #pragma unroll
    for (int ntd = 0; ntd < 2; ++ntd) {
      f32x4 oa = ntd ? oa1 : oa0;
      u32 lo = (u32)f2bf(oa[0]) | ((u32)f2bf(oa[1]) << 16);
      u32 hi = (u32)f2bf(oa[2]) | ((u32)f2bf(oa[3]) << 16);
      int d = ntd * 16 + c16;
      size_t off = ((size_t)((b * C_ + head * D_ + d) * 128 + line)) * 128 + mt * 16 + rg * 4;
      uint2 st; st.x = lo; st.y = hi;
      *(uint2*)(ob + off) = st;
    }
  }
}

// ---------------------------------------------------------------------------
// k_conv: combine out_h + out_w^T, depthwise 3x3 SAME conv; bf16 out now.
// ---------------------------------------------------------------------------
__global__ __launch_bounds__(256) void k_conv(const u16* __restrict__ hb,
                                              const u16* __restrict__ wb,
                                              const float* __restrict__ wdw,
                                              u16* __restrict__ convo) {
  __shared__ u16 t[128 * 136];
  const int tid = threadIdx.x;
  const int c = blockIdx.x, b = blockIdx.y;
  const size_t pb = (size_t)(b * C_ + c) * HW_;

  for (int i = tid; i < 2048; i += 256) {
    int e = i * 8; int r = e >> 7, col = e & 127;
    *(uint4*)&t[r * 136 + col] = *(const uint4*)(hb + pb + e);
  }
  __syncthreads();
  for (int i = tid; i < 4096; i += 256) {
    int e = i * 4; int wr = e >> 7, hc = e & 127;
    u32 u2[2]; *(uint2*)u2 = *(const uint2*)(wb + pb + e);
    float f0 = bflo(u2[0]), f1 = bfhi(u2[0]), f2v = bflo(u2[1]), f3 = bfhi(u2[1]);
    t[(hc + 0) * 136 + wr] = f2bf(bf2f_u(t[(hc + 0) * 136 + wr]) + f0);
    t[(hc + 1) * 136 + wr] = f2bf(bf2f_u(t[(hc + 1) * 136 + wr]) + f1);
    t[(hc + 2) * 136 + wr] = f2bf(bf2f_u(t[(hc + 2) * 136 + wr]) + f2v);
    t[(hc + 3) * 136 + wr] = f2bf(bf2f_u(t[(hc + 3) * 136 + wr]) + f3);
  }
  __syncthreads();

  float k9[9];
  #pragma unroll
  for (int i = 0; i < 9; ++i) k9[i] = wdw[c * 9 + i];

  for (int px = tid; px < HW_; px += 256) {
    int r = px >> 7, col = px & 127;
    float a = 0.f;
    #pragma unroll
    for (int di = 0; di < 3; ++di) {
      int rr = r + di - 1;
      if (rr < 0 || rr > 127) continue;
      #pragma unroll
      for (int dj = 0; dj < 3; ++dj) {
        int cc2 = col + dj - 1;
        if (cc2 < 0 || cc2 > 127) continue;
        a += k9[di * 3 + dj] * bf2f_u(t[rr * 136 + cc2]);
      }
    }
    convo[pb + px] = f2bf(a);
  }
}

// ---------------------------------------------------------------------------
extern "C" void kernel_launch(void* const* d_in, const int* in_sizes, int n_in,
                              void* d_out, int out_size, void* d_ws, size_t ws_size,
                              hipStream_t stream) {
  const float* x     = (const float*)d_in[0];
  const float* wqkv  = (const float*)d_in[1];
  const float* wproj = (const float*)d_in[2];
  const float* wdw   = (const float*)d_in[3];
  const float* gamma = (const float*)d_in[4];
  float* out = (float*)d_out;
  char* ws = (char*)d_ws;

  // workspace (max 224 MB, same peak as R2):
  u16* q   = (u16*)(ws);                    // 32 MB [B,4,HW,32] bf16
  u16* k   = (u16*)(ws + 33554432ull);      // 32 MB
  u16* v   = (u16*)(ws + 67108864ull);      // 32 MB
  u16* hb  = (u16*)(ws + 100663296ull);     // 32 MB [B,C,H,W] bf16 (attn-H out)
  u16* wb  = (u16*)(ws + 134217728ull);     // 32 MB [B,C,W,H] bf16 (attn-W out)
  u16* cv  = (u16*)(ws + 167772160ull);     // 32 MB [B,C,HW] bf16 (conv out)
  u16* xT  = (u16*)(ws + 201326592ull);     // 32 MB [B,HW,C] bf16 (also cvT later)
  u16* wqb = hb;                            // 96 KB, dead until attn writes hb
  u16* wpb = q;                             // 32 KB, q dead after attn

  k_wcvt     <<<dim3(48),        256, 0, stream>>>(wqkv, wqb, 12288);
  t_f32      <<<dim3(128, 1, 8), 256, 0, stream>>>(x, xT);
  k_qkv      <<<dim3(128, 1, 8), 256, 0, stream>>>(xT, wqb, q);
  k_attn_mfma<<<dim3(32, 8, 8),  256, 0, stream>>>(q, k, v, gamma, hb, wb);
  k_conv     <<<dim3(128, 8),    256, 0, stream>>>(hb, wb, wdw, cv);
  k_wcvt     <<<dim3(16),        256, 0, stream>>>(wproj, wpb, 4096);
  t_bf16     <<<dim3(128, 1, 8), 256, 0, stream>>>(cv, xT);
  k_proj     <<<dim3(128, 1, 8), 256, 0, stream>>>(xT, wpb, out);
}

// Round 4
// 389.307 us; speedup vs baseline: 2.4377x; 1.0411x over previous
//
#include <hip/hip_runtime.h>

typedef unsigned short u16;
typedef unsigned int   u32;
typedef short bf16x8 __attribute__((ext_vector_type(8)));
typedef float f32x4  __attribute__((ext_vector_type(4)));

#define B_   8
#define C_   128
#define H_   128
#define W_   128
#define NH   4
#define D_   32
#define HW_  16384
#define SCALE 0.17677669529663687f
#define SCL2E 0.2550437602866803f   // SCALE * log2(e)

__device__ __forceinline__ float bf2f_u(u16 u) { union { u32 i; float f; } x; x.i = ((u32)u) << 16; return x.f; }
__device__ __forceinline__ float bflo(u32 u)   { union { u32 i; float f; } x; x.i = u << 16; return x.f; }
__device__ __forceinline__ float bfhi(u32 u)   { union { u32 i; float f; } x; x.i = u & 0xffff0000u; return x.f; }
__device__ __forceinline__ u16   f2bf(float f) {
  union { float f; u32 i; } x; x.f = f;
  u32 i = x.i;
  return (u16)((i + 0x7fffu + ((i >> 16) & 1u)) >> 16);
}
__device__ __forceinline__ u32 pk2(float a, float b) {
  return (u32)f2bf(a) | ((u32)f2bf(b) << 16);
}
__device__ __forceinline__ bf16x8 ld_frag_g(const u16* p) {
  union { uint4 u; bf16x8 f; } c; c.u = *(const uint4*)p; return c.f;
}

// ---------------------------------------------------------------------------
// k_wcvt: f32 weights -> bf16, row-major preserved. n4 = count of float4s.
// ---------------------------------------------------------------------------
__global__ __launch_bounds__(256) void k_wcvt(const float* __restrict__ src,
                                              u16* __restrict__ dst, int n4) {
  int i = blockIdx.x * 256 + threadIdx.x;
  if (i < n4) {
    float4 v = ((const float4*)src)[i];
    uint2 st; st.x = pk2(v.x, v.y); st.y = pk2(v.z, v.w);
    *(uint2*)(dst + (size_t)i * 4) = st;
  }
}

// ---------------------------------------------------------------------------
// t_f32: x [b][c][p] f32 -> xT [b][p][c] bf16.
// ---------------------------------------------------------------------------
__global__ __launch_bounds__(256) void t_f32(const float* __restrict__ src,
                                             u16* __restrict__ dst) {
  __shared__ u32 tile[128 * 65];
  const int tid = threadIdx.x, w = tid >> 6, lane = tid & 63;
  const int b = blockIdx.z;
  const int P0 = blockIdx.x * 128;
  const float* sb = src + (size_t)b * C_ * HW_ + P0;

  #pragma unroll
  for (int ci = 0; ci < 4; ++ci) {
    int cp = 16 * w + 4 * ci + (lane >> 4);
    #pragma unroll
    for (int ph = 0; ph < 2; ++ph) {
      int p = 4 * (lane & 15) + 64 * ph;
      const float* r0 = sb + (size_t)(2 * cp) * HW_ + p;
      float4 a  = *(const float4*)r0;
      float4 bb = *(const float4*)(r0 + HW_);
      tile[(p + 0) * 65 + cp] = pk2(a.x, bb.x);
      tile[(p + 1) * 65 + cp] = pk2(a.y, bb.y);
      tile[(p + 2) * 65 + cp] = pk2(a.z, bb.z);
      tile[(p + 3) * 65 + cp] = pk2(a.w, bb.w);
    }
  }
  __syncthreads();
  u32* db = (u32*)(dst + ((size_t)b * HW_ + P0) * 128);
  #pragma unroll
  for (int it = 0; it < 8; ++it) {
    int p  = (tid >> 4) + 16 * it;
    int dq = (tid & 15) * 4;
    uint4 v;
    v.x = tile[p * 65 + dq];     v.y = tile[p * 65 + dq + 1];
    v.z = tile[p * 65 + dq + 2]; v.w = tile[p * 65 + dq + 3];
    *(uint4*)(db + p * 64 + dq) = v;
  }
}

// ---------------------------------------------------------------------------
// t_bf16: cv [b][c][p] bf16 -> cvT [b][p][c] bf16.
// ---------------------------------------------------------------------------
__global__ __launch_bounds__(256) void t_bf16(const u16* __restrict__ src,
                                              u16* __restrict__ dst) {
  __shared__ u32 tile[128 * 65];
  const int tid = threadIdx.x, w = tid >> 6, lane = tid & 63;
  const int b = blockIdx.z;
  const int P0 = blockIdx.x * 128;
  const u16* sb = src + (size_t)b * C_ * HW_ + P0;

  #pragma unroll
  for (int ci = 0; ci < 4; ++ci) {
    int cp = 16 * w + 4 * ci + (lane >> 4);
    #pragma unroll
    for (int ph = 0; ph < 2; ++ph) {
      int p = 4 * (lane & 15) + 64 * ph;
      const u16* r0 = sb + (size_t)(2 * cp) * HW_ + p;
      uint2 a  = *(const uint2*)r0;
      uint2 bb = *(const uint2*)(r0 + HW_);
      tile[(p + 0) * 65 + cp] = (a.x & 0xffffu) | (bb.x << 16);
      tile[(p + 1) * 65 + cp] = (a.x >> 16)     | (bb.x & 0xffff0000u);
      tile[(p + 2) * 65 + cp] = (a.y & 0xffffu) | (bb.y << 16);
      tile[(p + 3) * 65 + cp] = (a.y >> 16)     | (bb.y & 0xffff0000u);
    }
  }
  __syncthreads();
  u32* db = (u32*)(dst + ((size_t)b * HW_ + P0) * 128);
  #pragma unroll
  for (int it = 0; it < 8; ++it) {
    int p  = (tid >> 4) + 16 * it;
    int dq = (tid & 15) * 4;
    uint4 v;
    v.x = tile[p * 65 + dq];     v.y = tile[p * 65 + dq + 1];
    v.z = tile[p * 65 + dq + 2]; v.w = tile[p * 65 + dq + 3];
    *(uint4*)(db + p * 64 + dq) = v;
  }
}

// ---------------------------------------------------------------------------
// k_qkv: streaming MFMA GEMM. xT [b][p][128c] bf16, wqb [384][128] bf16.
// ---------------------------------------------------------------------------
__global__ __launch_bounds__(256) void k_qkv(const u16* __restrict__ xT,
                                             const u16* __restrict__ wqb,
                                             u16* __restrict__ qkvb) {
  const int tid = threadIdx.x, w = tid >> 6, lane = tid & 63;
  const int c16 = lane & 15, rg = lane >> 4;
  const int b = blockIdx.z;
  const int p0 = blockIdx.x * 128 + w * 32;
  const u16* xb = xT + ((size_t)b * HW_ + p0) * 128;

  bf16x8 bfr[2][4];
  #pragma unroll
  for (int nt = 0; nt < 2; ++nt)
    #pragma unroll
    for (int kk = 0; kk < 4; ++kk)
      bfr[nt][kk] = ld_frag_g(xb + (size_t)(nt * 16 + c16) * 128 + kk * 32 + rg * 8);

  const f32x4 zero = {0.f, 0.f, 0.f, 0.f};
  #pragma unroll 1
  for (int pass = 0; pass < 3; ++pass) {
    f32x4 acc[8][2];
    #pragma unroll
    for (int mt = 0; mt < 8; ++mt) { acc[mt][0] = zero; acc[mt][1] = zero; }

    #pragma unroll
    for (int kk = 0; kk < 4; ++kk) {
      #pragma unroll
      for (int mt = 0; mt < 8; ++mt) {
        bf16x8 af = ld_frag_g(wqb + (size_t)(pass * 128 + mt * 16 + c16) * 128 + kk * 32 + rg * 8);
        acc[mt][0] = __builtin_amdgcn_mfma_f32_16x16x32_bf16(af, bfr[0][kk], acc[mt][0], 0, 0, 0);
        acc[mt][1] = __builtin_amdgcn_mfma_f32_16x16x32_bf16(af, bfr[1][kk], acc[mt][1], 0, 0, 0);
      }
    }

    u16* ob = qkvb + (size_t)pass * ((size_t)B_ * NH * HW_ * D_);
    #pragma unroll
    for (int mt = 0; mt < 8; ++mt) {
      int head = mt >> 1, d0 = (mt & 1) * 16 + rg * 4;
      #pragma unroll
      for (int nt = 0; nt < 2; ++nt) {
        f32x4 oa = acc[mt][nt];
        uint2 st;
        st.x = pk2(oa[0], oa[1]);
        st.y = pk2(oa[2], oa[3]);
        int pix = p0 + nt * 16 + c16;
        *(uint2*)(ob + ((size_t)(b * NH + head) * HW_ + pix) * 32 + d0) = st;
      }
    }
  }
}

// ---------------------------------------------------------------------------
// k_proj: streaming MFMA GEMM. cvT [b][p][128c] bf16 -> out f32 NCHW.
// ---------------------------------------------------------------------------
__global__ __launch_bounds__(256) void k_proj(const u16* __restrict__ cvT,
                                              const u16* __restrict__ wpb,
                                              float* __restrict__ out) {
  const int tid = threadIdx.x, w = tid >> 6, lane = tid & 63;
  const int c16 = lane & 15, rg = lane >> 4;
  const int b = blockIdx.z;
  const int p0 = blockIdx.x * 128 + w * 32;
  const u16* xb = cvT + ((size_t)b * HW_ + p0) * 128;

  bf16x8 bfr[2][4];
  #pragma unroll
  for (int nt = 0; nt < 2; ++nt)
    #pragma unroll
    for (int kk = 0; kk < 4; ++kk)
      bfr[nt][kk] = ld_frag_g(xb + (size_t)(nt * 16 + c16) * 128 + kk * 32 + rg * 8);

  const f32x4 zero = {0.f, 0.f, 0.f, 0.f};
  f32x4 acc[8][2];
  #pragma unroll
  for (int mt = 0; mt < 8; ++mt) { acc[mt][0] = zero; acc[mt][1] = zero; }

  #pragma unroll
  for (int kk = 0; kk < 4; ++kk) {
    #pragma unroll
    for (int mt = 0; mt < 8; ++mt) {
      bf16x8 af = ld_frag_g(wpb + (size_t)(mt * 16 + c16) * 128 + kk * 32 + rg * 8);
      acc[mt][0] = __builtin_amdgcn_mfma_f32_16x16x32_bf16(af, bfr[0][kk], acc[mt][0], 0, 0, 0);
      acc[mt][1] = __builtin_amdgcn_mfma_f32_16x16x32_bf16(af, bfr[1][kk], acc[mt][1], 0, 0, 0);
    }
  }

  float* ob = out + (size_t)b * C_ * HW_;
  #pragma unroll
  for (int mt = 0; mt < 8; ++mt) {
    #pragma unroll
    for (int nt = 0; nt < 2; ++nt) {
      f32x4 oa = acc[mt][nt];
      int pix = p0 + nt * 16 + c16;
      #pragma unroll
      for (int r = 0; r < 4; ++r) {
        int o = mt * 16 + rg * 4 + r;
        ob[(size_t)o * HW_ + pix] = oa[r];
      }
    }
  }
}

// ---------------------------------------------------------------------------
// k_attn_mfma: wave-per-line MFMA flash attention, both axes.
// R4: pt aliases vt (LDS 34816/block -> 4 blocks/CU); no max-subtract pass
// (scores provably small); qf software-pipelined one tile ahead.
// ---------------------------------------------------------------------------
__global__ __launch_bounds__(256) void k_attn_mfma(const u16* __restrict__ qb,
                                                   const u16* __restrict__ kb,
                                                   const u16* __restrict__ vb,
                                                   const float* __restrict__ gp,
                                                   u16* __restrict__ houtb,
                                                   u16* __restrict__ woutb) {
  __shared__ u32 lds[4][32 * 68];
  const int tid  = threadIdx.x;
  const int w    = tid >> 6;
  const int lane = tid & 63;
  const int head = blockIdx.y & 3;
  const int axis = blockIdx.y >> 2;
  const int b    = blockIdx.z;
  const int line = blockIdx.x * 4 + w;
  u32* vt = &lds[w][0];
  u32* pt = &lds[w][0];          // alias: vt dead after vf frags resident
  const size_t base = (size_t)(b * NH + head) * HW_ * D_;
  const float g = gp[0];
  const int c16 = lane & 15, rg = lane >> 4;
  const size_t pstride = axis ? (size_t)128 * D_ : (size_t)D_;
  const size_t lbase   = base + (size_t)line * (axis ? D_ : 128 * D_);

  // ---- stage V^T (pair-packed along z) ----
  {
    const u16* v0p = vb + lbase + (size_t)(2 * lane) * pstride;
    const u16* v1p = v0p + pstride;
    u32 v0r[16], v1r[16];
    #pragma unroll
    for (int t = 0; t < 4; ++t) {
      *(uint4*)&v0r[4 * t] = *(const uint4*)(v0p + 8 * t);
      *(uint4*)&v1r[4 * t] = *(const uint4*)(v1p + 8 * t);
    }
    #pragma unroll
    for (int dw = 0; dw < 16; ++dw) {
      u32 a = v0r[dw], bq = v1r[dw];
      u32 lo = (a & 0xffffu) | (bq << 16);
      u32 hi = (a >> 16) | (bq & 0xffff0000u);
      vt[(2 * dw) * 68 + lane]     = lo;
      vt[(2 * dw + 1) * 68 + lane] = hi;
    }
  }

  // ---- K B-frags from global (resident) ----
  bf16x8 kf[8];
  #pragma unroll
  for (int nt = 0; nt < 8; ++nt)
    kf[nt] = ld_frag_g(kb + lbase + (size_t)(nt * 16 + c16) * pstride + rg * 8);

  // ---- V^T B-frags from LDS (resident; issued before any pt overwrite,
  //      DS is in-order per wave) ----
  bf16x8 vf[2][4];
  #pragma unroll
  for (int ntd = 0; ntd < 2; ++ntd)
    #pragma unroll
    for (int t = 0; t < 4; ++t) {
      union { uint4 u; bf16x8 f; } c;
      c.u = *(const uint4*)(vt + (ntd * 16 + c16) * 68 + t * 16 + rg * 4);
      vf[ntd][t] = c.f;
    }

  // ---- decay running products ----
  const float R16 = __expf(-16.f * g), Ri16 = __expf(16.f * g);
  const float R144 = __expf(-144.f * g), Ri144 = __expf(144.f * g);
  float F[4], Fi[4];
  #pragma unroll
  for (int r = 0; r < 4; ++r) {
    float t0 = (float)(c16 - (rg * 4 + r));
    F[r]  = __expf(-g * t0);
    Fi[r] = __expf(g * t0);
  }

  u16* ob = axis ? woutb : houtb;
  const f32x4 zero = {0.f, 0.f, 0.f, 0.f};

  bf16x8 qf = ld_frag_g(qb + lbase + (size_t)c16 * pstride + rg * 8);

  #pragma unroll 1
  for (int mt = 0; mt < 8; ++mt) {
    // prefetch next tile's Q frag (harmless reload on last iter)
    int mtn = mt < 7 ? mt + 1 : 7;
    bf16x8 qf_n = ld_frag_g(qb + lbase + (size_t)(mtn * 16 + c16) * pstride + rg * 8);

    f32x4 sa[8];
    #pragma unroll
    for (int nt = 0; nt < 8; ++nt)
      sa[nt] = __builtin_amdgcn_mfma_f32_16x16x32_bf16(qf, kf[nt], zero, 0, 0, 0);

    // softmax (no max-subtract: |s*scale| <~ 2) + decay + P pack to LDS
    #pragma unroll
    for (int r = 0; r < 4; ++r) {
      float l = 0.f;
      #pragma unroll
      for (int nt = 0; nt < 8; ++nt) {
        float e = __builtin_amdgcn_exp2f(sa[nt][r] * SCL2E);
        l += e;
        sa[nt][r] = e;
      }
      l += __shfl_xor(l, 1);
      l += __shfl_xor(l, 2);
      l += __shfl_xor(l, 4);
      l += __shfl_xor(l, 8);
      const float li = __builtin_amdgcn_rcpf(l);
      float f = F[r], fi = Fi[r];
      #pragma unroll
      for (int nt = 0; nt < 8; ++nt) {
        float pv = sa[nt][r] * (li * fminf(f, fi));
        f *= R16; fi *= Ri16;
        union { float f; u32 i; } cu; cu.f = pv;
        u32 u = (cu.i + 0x8000u) >> 16;
        u32 uo = (u32)__shfl_xor((int)u, 1);
        u32 dwv = (u & 0xffffu) | (uo << 16);
        if (!(lane & 1)) pt[(rg * 4 + r) * 68 + nt * 8 + (c16 >> 1)] = dwv;
      }
      F[r] = f * Ri144;
      Fi[r] = fi * R144;
    }

    // PV
    f32x4 oa0 = zero, oa1 = zero;
    #pragma unroll
    for (int t = 0; t < 4; ++t) {
      union { uint4 u; bf16x8 f; } af;
      af.u = *(const uint4*)(pt + c16 * 68 + t * 16 + rg * 4);
      oa0 = __builtin_amdgcn_mfma_f32_16x16x32_bf16(af.f, vf[0][t], oa0, 0, 0, 0);
      oa1 = __builtin_amdgcn_mfma_f32_16x16x32_bf16(af.f, vf[1][t], oa1, 0, 0, 0);
    }

    #pragma unroll
    for (int ntd = 0; ntd < 2; ++ntd) {
      f32x4 oa = ntd ? oa1 : oa0;
      u32 lo = (u32)f2bf(oa[0]) | ((u32)f2bf(oa[1]) << 16);
      u32 hi = (u32)f2bf(oa[2]) | ((u32)f2bf(oa[3]) << 16);
      int d = ntd * 16 + c16;
      size_t off = ((size_t)((b * C_ + head * D_ + d) * 128 + line)) * 128 + mt * 16 + rg * 4;
      uint2 st; st.x = lo; st.y = hi;
      *(uint2*)(ob + off) = st;
    }
    qf = qf_n;
  }
}

// ---------------------------------------------------------------------------
// k_conv: combine out_h + out_w^T, depthwise 3x3 SAME conv; bf16 out.
// ---------------------------------------------------------------------------
__global__ __launch_bounds__(256) void k_conv(const u16* __restrict__ hb,
                                              const u16* __restrict__ wb,
                                              const float* __restrict__ wdw,
                                              u16* __restrict__ convo) {
  __shared__ u16 t[128 * 136];
  const int tid = threadIdx.x;
  const int c = blockIdx.x, b = blockIdx.y;
  const size_t pb = (size_t)(b * C_ + c) * HW_;

  for (int i = tid; i < 2048; i += 256) {
    int e = i * 8; int r = e >> 7, col = e & 127;
    *(uint4*)&t[r * 136 + col] = *(const uint4*)(hb + pb + e);
  }
  __syncthreads();
  for (int i = tid; i < 4096; i += 256) {
    int e = i * 4; int wr = e >> 7, hc = e & 127;
    u32 u2[2]; *(uint2*)u2 = *(const uint2*)(wb + pb + e);
    float f0 = bflo(u2[0]), f1 = bfhi(u2[0]), f2v = bflo(u2[1]), f3 = bfhi(u2[1]);
    t[(hc + 0) * 136 + wr] = f2bf(bf2f_u(t[(hc + 0) * 136 + wr]) + f0);
    t[(hc + 1) * 136 + wr] = f2bf(bf2f_u(t[(hc + 1) * 136 + wr]) + f1);
    t[(hc + 2) * 136 + wr] = f2bf(bf2f_u(t[(hc + 2) * 136 + wr]) + f2v);
    t[(hc + 3) * 136 + wr] = f2bf(bf2f_u(t[(hc + 3) * 136 + wr]) + f3);
  }
  __syncthreads();

  float k9[9];
  #pragma unroll
  for (int i = 0; i < 9; ++i) k9[i] = wdw[c * 9 + i];

  for (int px = tid; px < HW_; px += 256) {
    int r = px >> 7, col = px & 127;
    float a = 0.f;
    #pragma unroll
    for (int di = 0; di < 3; ++di) {
      int rr = r + di - 1;
      if (rr < 0 || rr > 127) continue;
      #pragma unroll
      for (int dj = 0; dj < 3; ++dj) {
        int cc2 = col + dj - 1;
        if (cc2 < 0 || cc2 > 127) continue;
        a += k9[di * 3 + dj] * bf2f_u(t[rr * 136 + cc2]);
      }
    }
    convo[pb + px] = f2bf(a);
  }
}

// ---------------------------------------------------------------------------
extern "C" void kernel_launch(void* const* d_in, const int* in_sizes, int n_in,
                              void* d_out, int out_size, void* d_ws, size_t ws_size,
                              hipStream_t stream) {
  const float* x     = (const float*)d_in[0];
  const float* wqkv  = (const float*)d_in[1];
  const float* wproj = (const float*)d_in[2];
  const float* wdw   = (const float*)d_in[3];
  const float* gamma = (const float*)d_in[4];
  float* out = (float*)d_out;
  char* ws = (char*)d_ws;

  u16* q   = (u16*)(ws);                    // 32 MB [B,4,HW,32] bf16
  u16* k   = (u16*)(ws + 33554432ull);      // 32 MB
  u16* v   = (u16*)(ws + 67108864ull);      // 32 MB
  u16* hb  = (u16*)(ws + 100663296ull);     // 32 MB [B,C,H,W] bf16 (attn-H out)
  u16* wb  = (u16*)(ws + 134217728ull);     // 32 MB [B,C,W,H] bf16 (attn-W out)
  u16* cv  = (u16*)(ws + 167772160ull);     // 32 MB [B,C,HW] bf16 (conv out)
  u16* xT  = (u16*)(ws + 201326592ull);     // 32 MB [B,HW,C] bf16 (also cvT later)
  u16* wqb = hb;                            // 96 KB, dead until attn writes hb
  u16* wpb = q;                             // 32 KB, q dead after attn

  k_wcvt     <<<dim3(48),        256, 0, stream>>>(wqkv, wqb, 12288);
  t_f32      <<<dim3(128, 1, 8), 256, 0, stream>>>(x, xT);
  k_qkv      <<<dim3(128, 1, 8), 256, 0, stream>>>(xT, wqb, q);
  k_attn_mfma<<<dim3(32, 8, 8),  256, 0, stream>>>(q, k, v, gamma, hb, wb);
  k_conv     <<<dim3(128, 8),    256, 0, stream>>>(hb, wb, wdw, cv);
  k_wcvt     <<<dim3(16),        256, 0, stream>>>(wproj, wpb, 4096);
  t_bf16     <<<dim3(128, 1, 8), 256, 0, stream>>>(cv, xT);
  k_proj     <<<dim3(128, 1, 8), 256, 0, stream>>>(xT, wpb, out);
}

// Round 5
// 363.522 us; speedup vs baseline: 2.6106x; 1.0709x over previous
//
#include <hip/hip_runtime.h>

typedef unsigned short u16;
typedef unsigned int   u32;
typedef short bf16x8 __attribute__((ext_vector_type(8)));
typedef float f32x4  __attribute__((ext_vector_type(4)));

#define B_   8
#define C_   128
#define H_   128
#define W_   128
#define NH   4
#define D_   32
#define HW_  16384
#define SCALE 0.17677669529663687f
#define SCL2E 0.2550437602866803f   // SCALE * log2(e)

__device__ __forceinline__ float bf2f_u(u16 u) { union { u32 i; float f; } x; x.i = ((u32)u) << 16; return x.f; }
__device__ __forceinline__ float bflo(u32 u)   { union { u32 i; float f; } x; x.i = u << 16; return x.f; }
__device__ __forceinline__ float bfhi(u32 u)   { union { u32 i; float f; } x; x.i = u & 0xffff0000u; return x.f; }
__device__ __forceinline__ u16   f2bf(float f) {
  union { float f; u32 i; } x; x.f = f;
  u32 i = x.i;
  return (u16)((i + 0x7fffu + ((i >> 16) & 1u)) >> 16);
}
__device__ __forceinline__ u32 pk2(float a, float b) {
  return (u32)f2bf(a) | ((u32)f2bf(b) << 16);
}
__device__ __forceinline__ bf16x8 ld_frag_g(const u16* p) {
  union { uint4 u; bf16x8 f; } c; c.u = *(const uint4*)p; return c.f;
}

// ---------------------------------------------------------------------------
// k_wcvt2: convert both weight tensors f32 -> bf16 in one launch.
// wqkv: 12288 float4s, wproj: 4096 float4s.
// ---------------------------------------------------------------------------
__global__ __launch_bounds__(256) void k_wcvt2(const float* __restrict__ wq,
                                               const float* __restrict__ wp,
                                               u16* __restrict__ dq,
                                               u16* __restrict__ dp) {
  int i = blockIdx.x * 256 + threadIdx.x;
  const float* src; u16* dst; int j;
  if (i < 12288) { src = wq; dst = dq; j = i; }
  else           { src = wp; dst = dp; j = i - 12288; }
  float4 v = ((const float4*)src)[j];
  uint2 st; st.x = pk2(v.x, v.y); st.y = pk2(v.z, v.w);
  *(uint2*)(dst + (size_t)j * 4) = st;
}

// ---------------------------------------------------------------------------
// k_qkv: fused transpose + MFMA GEMM. x [b][c][p] f32 staged in LDS as
// [p][cp] pair-packed bf16 (stride 65 dw), B-frags read from LDS,
// A = wqb [384][128] bf16 streamed from global (L2-hot).
// Output q/k/v each [b][head][pix][32d] bf16.
// ---------------------------------------------------------------------------
__global__ __launch_bounds__(256) void k_qkv(const float* __restrict__ x,
                                             const u16* __restrict__ wqb,
                                             u16* __restrict__ qkvb) {
  __shared__ u32 tile[128 * 65];
  const int tid = threadIdx.x, w = tid >> 6, lane = tid & 63;
  const int c16 = lane & 15, rg = lane >> 4;
  const int b = blockIdx.z;
  const int P0 = blockIdx.x * 128;
  const float* sb = x + (size_t)b * C_ * HW_ + P0;

  // stage (t_f32 write-side, proven ~conflict-free)
  #pragma unroll
  for (int ci = 0; ci < 4; ++ci) {
    int cp = 16 * w + 4 * ci + (lane >> 4);
    #pragma unroll
    for (int ph = 0; ph < 2; ++ph) {
      int p = 4 * (lane & 15) + 64 * ph;
      const float* r0 = sb + (size_t)(2 * cp) * HW_ + p;
      float4 a  = *(const float4*)r0;
      float4 bb = *(const float4*)(r0 + HW_);
      tile[(p + 0) * 65 + cp] = pk2(a.x, bb.x);
      tile[(p + 1) * 65 + cp] = pk2(a.y, bb.y);
      tile[(p + 2) * 65 + cp] = pk2(a.z, bb.z);
      tile[(p + 3) * 65 + cp] = pk2(a.w, bb.w);
    }
  }
  __syncthreads();

  const int pw = w * 32;
  bf16x8 bfr[2][4];
  #pragma unroll
  for (int nt = 0; nt < 2; ++nt)
    #pragma unroll
    for (int kk = 0; kk < 4; ++kk) {
      int p = pw + nt * 16 + c16;
      int cp0 = kk * 16 + rg * 4;
      union { u32 d[4]; bf16x8 f; } u;
      u.d[0] = tile[p * 65 + cp0];
      u.d[1] = tile[p * 65 + cp0 + 1];
      u.d[2] = tile[p * 65 + cp0 + 2];
      u.d[3] = tile[p * 65 + cp0 + 3];
      bfr[nt][kk] = u.f;
    }

  const int p0 = P0 + pw;
  const f32x4 zero = {0.f, 0.f, 0.f, 0.f};
  #pragma unroll 1
  for (int pass = 0; pass < 3; ++pass) {
    f32x4 acc[8][2];
    #pragma unroll
    for (int mt = 0; mt < 8; ++mt) { acc[mt][0] = zero; acc[mt][1] = zero; }

    #pragma unroll
    for (int kk = 0; kk < 4; ++kk) {
      #pragma unroll
      for (int mt = 0; mt < 8; ++mt) {
        bf16x8 af = ld_frag_g(wqb + (size_t)(pass * 128 + mt * 16 + c16) * 128 + kk * 32 + rg * 8);
        acc[mt][0] = __builtin_amdgcn_mfma_f32_16x16x32_bf16(af, bfr[0][kk], acc[mt][0], 0, 0, 0);
        acc[mt][1] = __builtin_amdgcn_mfma_f32_16x16x32_bf16(af, bfr[1][kk], acc[mt][1], 0, 0, 0);
      }
    }

    u16* ob = qkvb + (size_t)pass * ((size_t)B_ * NH * HW_ * D_);
    #pragma unroll
    for (int mt = 0; mt < 8; ++mt) {
      int head = mt >> 1, d0 = (mt & 1) * 16 + rg * 4;
      #pragma unroll
      for (int nt = 0; nt < 2; ++nt) {
        f32x4 oa = acc[mt][nt];
        uint2 st;
        st.x = pk2(oa[0], oa[1]);
        st.y = pk2(oa[2], oa[3]);
        int pix = p0 + nt * 16 + c16;
        *(uint2*)(ob + ((size_t)(b * NH + head) * HW_ + pix) * 32 + d0) = st;
      }
    }
  }
}

// ---------------------------------------------------------------------------
// k_proj: fused transpose + MFMA GEMM. cv [b][c][p] bf16 staged in LDS,
// A = wpb [128][128] bf16. Output f32 NCHW (d_out).
// ---------------------------------------------------------------------------
__global__ __launch_bounds__(256) void k_proj(const u16* __restrict__ cv,
                                              const u16* __restrict__ wpb,
                                              float* __restrict__ out) {
  __shared__ u32 tile[128 * 65];
  const int tid = threadIdx.x, w = tid >> 6, lane = tid & 63;
  const int c16 = lane & 15, rg = lane >> 4;
  const int b = blockIdx.z;
  const int P0 = blockIdx.x * 128;
  const u16* sb = cv + (size_t)b * C_ * HW_ + P0;

  // stage (t_bf16 write-side)
  #pragma unroll
  for (int ci = 0; ci < 4; ++ci) {
    int cp = 16 * w + 4 * ci + (lane >> 4);
    #pragma unroll
    for (int ph = 0; ph < 2; ++ph) {
      int p = 4 * (lane & 15) + 64 * ph;
      const u16* r0 = sb + (size_t)(2 * cp) * HW_ + p;
      uint2 a  = *(const uint2*)r0;
      uint2 bb = *(const uint2*)(r0 + HW_);
      tile[(p + 0) * 65 + cp] = (a.x & 0xffffu) | (bb.x << 16);
      tile[(p + 1) * 65 + cp] = (a.x >> 16)     | (bb.x & 0xffff0000u);
      tile[(p + 2) * 65 + cp] = (a.y & 0xffffu) | (bb.y << 16);
      tile[(p + 3) * 65 + cp] = (a.y >> 16)     | (bb.y & 0xffff0000u);
    }
  }
  __syncthreads();

  const int pw = w * 32;
  bf16x8 bfr[2][4];
  #pragma unroll
  for (int nt = 0; nt < 2; ++nt)
    #pragma unroll
    for (int kk = 0; kk < 4; ++kk) {
      int p = pw + nt * 16 + c16;
      int cp0 = kk * 16 + rg * 4;
      union { u32 d[4]; bf16x8 f; } u;
      u.d[0] = tile[p * 65 + cp0];
      u.d[1] = tile[p * 65 + cp0 + 1];
      u.d[2] = tile[p * 65 + cp0 + 2];
      u.d[3] = tile[p * 65 + cp0 + 3];
      bfr[nt][kk] = u.f;
    }

  const int p0 = P0 + pw;
  const f32x4 zero = {0.f, 0.f, 0.f, 0.f};
  f32x4 acc[8][2];
  #pragma unroll
  for (int mt = 0; mt < 8; ++mt) { acc[mt][0] = zero; acc[mt][1] = zero; }

  #pragma unroll
  for (int kk = 0; kk < 4; ++kk) {
    #pragma unroll
    for (int mt = 0; mt < 8; ++mt) {
      bf16x8 af = ld_frag_g(wpb + (size_t)(mt * 16 + c16) * 128 + kk * 32 + rg * 8);
      acc[mt][0] = __builtin_amdgcn_mfma_f32_16x16x32_bf16(af, bfr[0][kk], acc[mt][0], 0, 0, 0);
      acc[mt][1] = __builtin_amdgcn_mfma_f32_16x16x32_bf16(af, bfr[1][kk], acc[mt][1], 0, 0, 0);
    }
  }

  float* ob = out + (size_t)b * C_ * HW_;
  #pragma unroll
  for (int mt = 0; mt < 8; ++mt) {
    #pragma unroll
    for (int nt = 0; nt < 2; ++nt) {
      f32x4 oa = acc[mt][nt];
      int pix = p0 + nt * 16 + c16;
      #pragma unroll
      for (int r = 0; r < 4; ++r) {
        int o = mt * 16 + rg * 4 + r;
        ob[(size_t)o * HW_ + pix] = oa[r];
      }
    }
  }
}

// ---------------------------------------------------------------------------
// k_attn_mfma: wave-per-line MFMA flash attention, both axes.
// R5: 1/l deferred to the 8 output elements (P stored unnormalized).
// ---------------------------------------------------------------------------
__global__ __launch_bounds__(256) void k_attn_mfma(const u16* __restrict__ qb,
                                                   const u16* __restrict__ kb,
                                                   const u16* __restrict__ vb,
                                                   const float* __restrict__ gp,
                                                   u16* __restrict__ houtb,
                                                   u16* __restrict__ woutb) {
  __shared__ u32 lds[4][32 * 68];
  const int tid  = threadIdx.x;
  const int w    = tid >> 6;
  const int lane = tid & 63;
  const int head = blockIdx.y & 3;
  const int axis = blockIdx.y >> 2;
  const int b    = blockIdx.z;
  const int line = blockIdx.x * 4 + w;
  u32* vt = &lds[w][0];
  u32* pt = &lds[w][0];          // alias: vt dead after vf frags resident
  const size_t base = (size_t)(b * NH + head) * HW_ * D_;
  const float g = gp[0];
  const int c16 = lane & 15, rg = lane >> 4;
  const size_t pstride = axis ? (size_t)128 * D_ : (size_t)D_;
  const size_t lbase   = base + (size_t)line * (axis ? D_ : 128 * D_);

  // ---- stage V^T (pair-packed along z) ----
  {
    const u16* v0p = vb + lbase + (size_t)(2 * lane) * pstride;
    const u16* v1p = v0p + pstride;
    u32 v0r[16], v1r[16];
    #pragma unroll
    for (int t = 0; t < 4; ++t) {
      *(uint4*)&v0r[4 * t] = *(const uint4*)(v0p + 8 * t);
      *(uint4*)&v1r[4 * t] = *(const uint4*)(v1p + 8 * t);
    }
    #pragma unroll
    for (int dw = 0; dw < 16; ++dw) {
      u32 a = v0r[dw], bq = v1r[dw];
      u32 lo = (a & 0xffffu) | (bq << 16);
      u32 hi = (a >> 16) | (bq & 0xffff0000u);
      vt[(2 * dw) * 68 + lane]     = lo;
      vt[(2 * dw + 1) * 68 + lane] = hi;
    }
  }

  // ---- K B-frags from global (resident) ----
  bf16x8 kf[8];
  #pragma unroll
  for (int nt = 0; nt < 8; ++nt)
    kf[nt] = ld_frag_g(kb + lbase + (size_t)(nt * 16 + c16) * pstride + rg * 8);

  // ---- V^T B-frags from LDS (issued before pt overwrite; DS in-order) ----
  bf16x8 vf[2][4];
  #pragma unroll
  for (int ntd = 0; ntd < 2; ++ntd)
    #pragma unroll
    for (int t = 0; t < 4; ++t) {
      union { uint4 u; bf16x8 f; } c;
      c.u = *(const uint4*)(vt + (ntd * 16 + c16) * 68 + t * 16 + rg * 4);
      vf[ntd][t] = c.f;
    }

  // ---- decay running products ----
  const float R16 = __expf(-16.f * g), Ri16 = __expf(16.f * g);
  const float R144 = __expf(-144.f * g), Ri144 = __expf(144.f * g);
  float F[4], Fi[4];
  #pragma unroll
  for (int r = 0; r < 4; ++r) {
    float t0 = (float)(c16 - (rg * 4 + r));
    F[r]  = __expf(-g * t0);
    Fi[r] = __expf(g * t0);
  }

  u16* ob = axis ? woutb : houtb;
  const f32x4 zero = {0.f, 0.f, 0.f, 0.f};

  bf16x8 qf = ld_frag_g(qb + lbase + (size_t)c16 * pstride + rg * 8);

  #pragma unroll 1
  for (int mt = 0; mt < 8; ++mt) {
    int mtn = mt < 7 ? mt + 1 : 7;
    bf16x8 qf_n = ld_frag_g(qb + lbase + (size_t)(mtn * 16 + c16) * pstride + rg * 8);

    f32x4 sa[8];
    #pragma unroll
    for (int nt = 0; nt < 8; ++nt)
      sa[nt] = __builtin_amdgcn_mfma_f32_16x16x32_bf16(qf, kf[nt], zero, 0, 0, 0);

    // softmax (no max-subtract; scores provably small) + decay; P unnormalized
    float linv[4];
    #pragma unroll
    for (int r = 0; r < 4; ++r) {
      float l = 0.f;
      #pragma unroll
      for (int nt = 0; nt < 8; ++nt) {
        float e = __builtin_amdgcn_exp2f(sa[nt][r] * SCL2E);
        l += e;
        sa[nt][r] = e;
      }
      l += __shfl_xor(l, 1);
      l += __shfl_xor(l, 2);
      l += __shfl_xor(l, 4);
      l += __shfl_xor(l, 8);
      linv[r] = __builtin_amdgcn_rcpf(l);
      float f = F[r], fi = Fi[r];
      #pragma unroll
      for (int nt = 0; nt < 8; ++nt) {
        float pv = sa[nt][r] * fminf(f, fi);
        f *= R16; fi *= Ri16;
        union { float f; u32 i; } cu; cu.f = pv;
        u32 u = (cu.i + 0x8000u) >> 16;
        u32 uo = (u32)__shfl_xor((int)u, 1);
        u32 dwv = (u & 0xffffu) | (uo << 16);
        if (!(lane & 1)) pt[(rg * 4 + r) * 68 + nt * 8 + (c16 >> 1)] = dwv;
      }
      F[r] = f * Ri144;
      Fi[r] = fi * R144;
    }

    // PV
    f32x4 oa0 = zero, oa1 = zero;
    #pragma unroll
    for (int t = 0; t < 4; ++t) {
      union { uint4 u; bf16x8 f; } af;
      af.u = *(const uint4*)(pt + c16 * 68 + t * 16 + rg * 4);
      oa0 = __builtin_amdgcn_mfma_f32_16x16x32_bf16(af.f, vf[0][t], oa0, 0, 0, 0);
      oa1 = __builtin_amdgcn_mfma_f32_16x16x32_bf16(af.f, vf[1][t], oa1, 0, 0, 0);
    }

    #pragma unroll
    for (int ntd = 0; ntd < 2; ++ntd) {
      f32x4 oa = ntd ? oa1 : oa0;
      u32 lo = pk2(oa[0] * linv[0], oa[1] * linv[1]);
      u32 hi = pk2(oa[2] * linv[2], oa[3] * linv[3]);
      int d = ntd * 16 + c16;
      size_t off = ((size_t)((b * C_ + head * D_ + d) * 128 + line)) * 128 + mt * 16 + rg * 4;
      uint2 st; st.x = lo; st.y = hi;
      *(uint2*)(ob + off) = st;
    }
    qf = qf_n;
  }
}

// ---------------------------------------------------------------------------
// k_conv: combine out_h + out_w^T, depthwise 3x3 SAME conv; bf16 out.
// ---------------------------------------------------------------------------
__global__ __launch_bounds__(256) void k_conv(const u16* __restrict__ hb,
                                              const u16* __restrict__ wb,
                                              const float* __restrict__ wdw,
                                              u16* __restrict__ convo) {
  __shared__ u16 t[128 * 136];
  const int tid = threadIdx.x;
  const int c = blockIdx.x, b = blockIdx.y;
  const size_t pb = (size_t)(b * C_ + c) * HW_;

  for (int i = tid; i < 2048; i += 256) {
    int e = i * 8; int r = e >> 7, col = e & 127;
    *(uint4*)&t[r * 136 + col] = *(const uint4*)(hb + pb + e);
  }
  __syncthreads();
  for (int i = tid; i < 4096; i += 256) {
    int e = i * 4; int wr = e >> 7, hc = e & 127;
    u32 u2[2]; *(uint2*)u2 = *(const uint2*)(wb + pb + e);
    float f0 = bflo(u2[0]), f1 = bfhi(u2[0]), f2v = bflo(u2[1]), f3 = bfhi(u2[1]);
    t[(hc + 0) * 136 + wr] = f2bf(bf2f_u(t[(hc + 0) * 136 + wr]) + f0);
    t[(hc + 1) * 136 + wr] = f2bf(bf2f_u(t[(hc + 1) * 136 + wr]) + f1);
    t[(hc + 2) * 136 + wr] = f2bf(bf2f_u(t[(hc + 2) * 136 + wr]) + f2v);
    t[(hc + 3) * 136 + wr] = f2bf(bf2f_u(t[(hc + 3) * 136 + wr]) + f3);
  }
  __syncthreads();

  float k9[9];
  #pragma unroll
  for (int i = 0; i < 9; ++i) k9[i] = wdw[c * 9 + i];

  for (int px = tid; px < HW_; px += 256) {
    int r = px >> 7, col = px & 127;
    float a = 0.f;
    #pragma unroll
    for (int di = 0; di < 3; ++di) {
      int rr = r + di - 1;
      if (rr < 0 || rr > 127) continue;
      #pragma unroll
      for (int dj = 0; dj < 3; ++dj) {
        int cc2 = col + dj - 1;
        if (cc2 < 0 || cc2 > 127) continue;
        a += k9[di * 3 + dj] * bf2f_u(t[rr * 136 + cc2]);
      }
    }
    convo[pb + px] = f2bf(a);
  }
}

// ---------------------------------------------------------------------------
extern "C" void kernel_launch(void* const* d_in, const int* in_sizes, int n_in,
                              void* d_out, int out_size, void* d_ws, size_t ws_size,
                              hipStream_t stream) {
  const float* x     = (const float*)d_in[0];
  const float* wqkv  = (const float*)d_in[1];
  const float* wproj = (const float*)d_in[2];
  const float* wdw   = (const float*)d_in[3];
  const float* gamma = (const float*)d_in[4];
  float* out = (float*)d_out;
  char* ws = (char*)d_ws;

  u16* q   = (u16*)(ws);                    // 32 MB [B,4,HW,32] bf16
  u16* k   = (u16*)(ws + 33554432ull);      // 32 MB
  u16* v   = (u16*)(ws + 67108864ull);      // 32 MB
  u16* hb  = (u16*)(ws + 100663296ull);     // 32 MB [B,C,H,W] bf16 (attn-H out)
  u16* wb  = (u16*)(ws + 134217728ull);     // 32 MB [B,C,W,H] bf16 (attn-W out)
  u16* cv  = (u16*)(ws + 167772160ull);     // 32 MB [B,C,HW] bf16 (conv out)
  u16* wqb = (u16*)(ws + 201326592ull);     // 96 KB bf16 qkv weights
  u16* wpb = (u16*)(ws + 201326592ull + 131072ull); // 32 KB bf16 proj weights

  k_wcvt2    <<<dim3(64),        256, 0, stream>>>(wqkv, wproj, wqb, wpb);
  k_qkv      <<<dim3(128, 1, 8), 256, 0, stream>>>(x, wqb, q);
  k_attn_mfma<<<dim3(32, 8, 8),  256, 0, stream>>>(q, k, v, gamma, hb, wb);
  k_conv     <<<dim3(128, 8),    256, 0, stream>>>(hb, wb, wdw, cv);
  k_proj     <<<dim3(128, 1, 8), 256, 0, stream>>>(cv, wpb, out);
}